// Round 12
// baseline (58.930 us; speedup 1.0000x reference)
//
#include <hip/hip_runtime.h>

#define NN 16
#define NO 32
#define XCOLS 133

typedef _Float16 h8v __attribute__((ext_vector_type(8)));
typedef _Float16 h2 __attribute__((ext_vector_type(2)));
typedef float f4v __attribute__((ext_vector_type(4)));
typedef unsigned ui4 __attribute__((ext_vector_type(4)));
typedef float f2u __attribute__((ext_vector_type(2), aligned(4)));

static __device__ __forceinline__ f4v MFMA(h8v a, h8v b, f4v c) {
    return __builtin_amdgcn_mfma_f32_16x16x32_f16(a, b, c, 0, 0, 0);
}
static __device__ __forceinline__ unsigned pkbits(float a, float b) {
    return __builtin_bit_cast(unsigned, __builtin_amdgcn_cvt_pkrtz(a, b));
}
static __device__ __forceinline__ h2 u2h(unsigned v) { return __builtin_bit_cast(h2, v); }

// ---------------------------------------------------------------------------
// prep (parallel, verified): pack weights into MFMA B-fragment arrays.
// B[k][col]: col = 16*nt + (lane&15), k = 32*kc + 8*(lane>>4) + j; zero-padded.
// ---------------------------------------------------------------------------
__global__ void prep_frags(
    const float* __restrict__ pnW1, const float* __restrict__ pnW2,
    const float* __restrict__ rnW1, const float* __restrict__ rnW2,
    const float* __restrict__ poW1, const float* __restrict__ poW2,
    const float* __restrict__ roW1, const float* __restrict__ roW2,
    const float* __restrict__ psW1, const float* __restrict__ psW2,
    const float* __restrict__ psW3, unsigned* __restrict__ ws)
{
    const float* Ws[11] = {pnW1,pnW2,rnW1,rnW2,poW1,poW2,roW1,roW2,psW1,psW2,psW3};
    const int Kr[11]   = {4,64,16,64,2,64,16,64,18,64,64};
    const int Nr[11]   = {64,16,64,8,64,16,64,8,64,64,2};
    const int nkc[11]  = {1,2,1,2,1,2,1,2,1,2,2};
    const int nnt[11]  = {4,1,4,1,4,1,4,1,4,4,1};
    const int base[11] = {0,1024,1536,2560,3072,4096,4608,5632,6144,7168,9216};

    const int gid = blockIdx.x * 256 + threadIdx.x;   // 0..9727
    int start = 0;
    #pragma unroll
    for (int a2 = 0; a2 < 11; ++a2) {
        const int n = nkc[a2] * nnt[a2] * 256;
        if (gid >= start && gid < start + n) {
            const int i = gid - start;
            const float* Wm = Ws[a2];
            const int K = Kr[a2], N = Nr[a2], nt_n = nnt[a2];
            const int d = i & 3, lane = (i >> 2) & 63, t = i >> 8;
            const int nt = t % nt_n, kc = t / nt_n;
            const int k = kc * 32 + 8 * (lane >> 4) + 2 * d;
            const int col = nt * 16 + (lane & 15);
            const float v0 = (k     < K && col < N) ? Wm[(k    ) * N + col] : 0.f;
            const float v1 = (k + 1 < K && col < N) ? Wm[(k + 1) * N + col] : 0.f;
            ws[base[a2] + i] = pkbits(v0, v1);
        }
        start += n;
    }
}

// ---------------------------------------------------------------------------
// main: 64-thread (1-wave) blocks; each wave runs TWO independent 16-element
// streams (s=0: rows 0..15, s=1: rows 16..31) through the whole pipeline,
// sharing B-fragment and bias registers. 2x ILP per wave vs R11; VGPR cap 256
// via __launch_bounds__(64,2) (R10's spill came from doubled B-frags — here
// B is shared so only A/acc double).
// LDS: XS[32][66] u32 (8448B) + 2x W(3136 f16: POOL@0 TBUF@1024 PN@2048
// HB@2560 barf@3072) = 12544B. Total 20992B.
// ---------------------------------------------------------------------------
__global__ __launch_bounds__(64, 2) void barrier_net_kernel(
    const float* __restrict__ x, const float* __restrict__ noise,
    const float* __restrict__ pnb1, const float* __restrict__ pnb2,
    const float* __restrict__ rnb1, const float* __restrict__ rnb2,
    const float* __restrict__ pob1, const float* __restrict__ pob2,
    const float* __restrict__ rob1, const float* __restrict__ rob2,
    const float* __restrict__ psb1, const float* __restrict__ psb2,
    const float* __restrict__ psb3,
    const unsigned* __restrict__ wsu, float* __restrict__ out)
{
    __shared__ unsigned XS[32 * 66];
    __shared__ _Float16 W[2 * 3136];

    const int l = threadIdx.x;
    const int r = l & 15;
    const int g = l >> 4;
    const int eb = blockIdx.x * 32;

    const h8v* FB = (const h8v*)wsu;
    const int sw8 = (r & 7) << 3;
    const int sw4 = (r & 3) << 3;

    // ---- burst-stage x: 32 rows x 128 floats (cols 5..132) + goal (cols 1,2)
    {
        const float* base = x + (size_t)eb * XCOLS;
        #pragma unroll
        for (int half = 0; half < 2; ++half) {
            f2u raw[16];
            #pragma unroll
            for (int it = 0; it < 16; ++it)
                raw[it] = *(const f2u*)(base + (size_t)(16 * half + it) * XCOLS + 5 + 2 * l);
            #pragma unroll
            for (int it = 0; it < 16; ++it)
                XS[(16 * half + it) * 66 + l] = pkbits(raw[it][0], raw[it][1]);
        }
        if (l < 32) {
            const f2u graw = *(const f2u*)(base + (size_t)l * XCOLS + 1);
            XS[l * 66 + 64] = pkbits(graw[0], graw[1]);
        }
    }

    {   // zero PN+HB for both streams (2 x 512 dwords)
        #pragma unroll
        for (int s = 0; s < 2; ++s) {
            unsigned* z = (unsigned*)(W + s * 3136 + 2048);
            #pragma unroll
            for (int i = 0; i < 8; ++i) z[l + 64 * i] = 0u;
        }
    }

    // ================= barrier pass + goal -> HB, per stream ==================
    #pragma unroll
    for (int s = 0; s < 2; ++s) {
        _Float16* Ws_ = W + s * 3136;
        float* barf = (float*)(Ws_ + 3072);
        const int rowb = (16 * s + r) * 66;
        float bq0 = 0.f, bq1 = 0.f;
        #pragma unroll
        for (int jj = 0; jj < 4; ++jj) {
            const h2 v = u2h(XS[rowb + 2 * (4 * g + jj)]);
            const float v0 = (float)v[0], v1 = (float)v[1];
            const float nrm = sqrtf(v0*v0 + v1*v1);
            const float cc = 0.01f * __builtin_amdgcn_rcpf(nrm * (nrm - 0.3f));
            bq0 -= cc * v0; bq1 -= cc * v1;
        }
        #pragma unroll
        for (int jj = 0; jj < 8; ++jj) {
            const h2 v = u2h(XS[rowb + 32 + 8 * g + jj]);
            const float v0 = (float)v[0], v1 = (float)v[1];
            const float nrm = sqrtf(v0*v0 + v1*v1);
            const float cc = 0.01f * __builtin_amdgcn_rcpf(nrm * (nrm - 0.5f));
            bq0 -= cc * v0; bq1 -= cc * v1;
        }
        bq0 += __shfl_xor(bq0, 16); bq0 += __shfl_xor(bq0, 32);
        bq1 += __shfl_xor(bq1, 16); bq1 += __shfl_xor(bq1, 32);
        if (g == 0) {
            barf[2*r] = bq0; barf[2*r + 1] = bq1;
            const h2 gv = u2h(XS[rowb + 64]);
            Ws_[2560 + r*32 + (16 ^ sw4)] = gv[0];
            Ws_[2560 + r*32 + (17 ^ sw4)] = gv[1];
        }
    }

    const int rowbA = r * 66;
    const int rowbB = (16 + r) * 66;

    // ================= L1 neighbor: both streams, shared B ====================
    {
        const h8v B0 = FB[0*64 + l], B1 = FB[1*64 + l];
        const h8v B2 = FB[2*64 + l], B3 = FB[3*64 + l];
        const f4v c0 = {pnb1[r], pnb1[r], pnb1[r], pnb1[r]};
        const f4v c1 = {pnb1[16+r], pnb1[16+r], pnb1[16+r], pnb1[16+r]};
        const f4v c2 = {pnb1[32+r], pnb1[32+r], pnb1[32+r], pnb1[32+r]};
        const f4v c3 = {pnb1[48+r], pnb1[48+r], pnb1[48+r], pnb1[48+r]};
        f4v sA0 = {0,0,0,0}, sA1 = {0,0,0,0}, sA2 = {0,0,0,0}, sA3 = {0,0,0,0};
        f4v sB0 = {0,0,0,0}, sB1 = {0,0,0,0}, sB2 = {0,0,0,0}, sB3 = {0,0,0,0};
        #pragma unroll 4
        for (int j = 0; j < NN; ++j) {
            const uint2 npA = *(const uint2*)&XS[rowbA + 2 * j];
            const uint2 npB = *(const uint2*)&XS[rowbB + 2 * j];
            ui4 auA = {npA.x, npA.y, 0u, 0u};
            ui4 auB = {npB.x, npB.y, 0u, 0u};
            const h8v aA = __builtin_bit_cast(h8v, auA);
            const h8v aB = __builtin_bit_cast(h8v, auB);
            const f4v dA0 = MFMA(aA, B0, c0);
            const f4v dA1 = MFMA(aA, B1, c1);
            const f4v dA2 = MFMA(aA, B2, c2);
            const f4v dA3 = MFMA(aA, B3, c3);
            const f4v dB0 = MFMA(aB, B0, c0);
            const f4v dB1 = MFMA(aB, B1, c1);
            const f4v dB2 = MFMA(aB, B2, c2);
            const f4v dB3 = MFMA(aB, B3, c3);
            #pragma unroll
            for (int q = 0; q < 4; ++q) {
                sA0[q] += fmaxf(dA0[q], 0.f); sA1[q] += fmaxf(dA1[q], 0.f);
                sA2[q] += fmaxf(dA2[q], 0.f); sA3[q] += fmaxf(dA3[q], 0.f);
                sB0[q] += fmaxf(dB0[q], 0.f); sB1[q] += fmaxf(dB1[q], 0.f);
                sB2[q] += fmaxf(dB2[q], 0.f); sB3[q] += fmaxf(dB3[q], 0.f);
            }
        }
        #pragma unroll
        for (int q = 0; q < 4; ++q) {
            const int e = 4 * g + q;
            const int m = (e & 7) << 3;
            W[e*64 + (( 0 + r) ^ m)] = (_Float16)sA0[q];
            W[e*64 + ((16 + r) ^ m)] = (_Float16)sA1[q];
            W[e*64 + ((32 + r) ^ m)] = (_Float16)sA2[q];
            W[e*64 + ((48 + r) ^ m)] = (_Float16)sA3[q];
            W[3136 + e*64 + (( 0 + r) ^ m)] = (_Float16)sB0[q];
            W[3136 + e*64 + ((16 + r) ^ m)] = (_Float16)sB1[q];
            W[3136 + e*64 + ((32 + r) ^ m)] = (_Float16)sB2[q];
            W[3136 + e*64 + ((48 + r) ^ m)] = (_Float16)sB3[q];
        }
    }

    // ================= L1 obstacle: both streams, shared B, 2 pts/iter ========
    {
        const h8v B0 = FB[768 + 0*64 + l], B1 = FB[768 + 1*64 + l];
        const h8v B2 = FB[768 + 2*64 + l], B3 = FB[768 + 3*64 + l];
        const f4v c0 = {pob1[r], pob1[r], pob1[r], pob1[r]};
        const f4v c1 = {pob1[16+r], pob1[16+r], pob1[16+r], pob1[16+r]};
        const f4v c2 = {pob1[32+r], pob1[32+r], pob1[32+r], pob1[32+r]};
        const f4v c3 = {pob1[48+r], pob1[48+r], pob1[48+r], pob1[48+r]};
        f4v sA0 = {0,0,0,0}, sA1 = {0,0,0,0}, sA2 = {0,0,0,0}, sA3 = {0,0,0,0};
        f4v sB0 = {0,0,0,0}, sB1 = {0,0,0,0}, sB2 = {0,0,0,0}, sB3 = {0,0,0,0};
        #pragma unroll 2
        for (int t = 0; t < 16; ++t) {
            const uint2 opA = *(const uint2*)&XS[rowbA + 32 + 2 * t];
            const uint2 opB = *(const uint2*)&XS[rowbB + 32 + 2 * t];
            ui4 aA0u = {opA.x, 0u, 0u, 0u}; ui4 aA1u = {opA.y, 0u, 0u, 0u};
            ui4 aB0u = {opB.x, 0u, 0u, 0u}; ui4 aB1u = {opB.y, 0u, 0u, 0u};
            const h8v aA0 = __builtin_bit_cast(h8v, aA0u);
            const h8v aA1 = __builtin_bit_cast(h8v, aA1u);
            const h8v aB0 = __builtin_bit_cast(h8v, aB0u);
            const h8v aB1 = __builtin_bit_cast(h8v, aB1u);
            const f4v dA0 = MFMA(aA0, B0, c0); const f4v eA0 = MFMA(aA1, B0, c0);
            const f4v dA1 = MFMA(aA0, B1, c1); const f4v eA1 = MFMA(aA1, B1, c1);
            const f4v dA2 = MFMA(aA0, B2, c2); const f4v eA2 = MFMA(aA1, B2, c2);
            const f4v dA3 = MFMA(aA0, B3, c3); const f4v eA3 = MFMA(aA1, B3, c3);
            const f4v dB0 = MFMA(aB0, B0, c0); const f4v eB0 = MFMA(aB1, B0, c0);
            const f4v dB1 = MFMA(aB0, B1, c1); const f4v eB1 = MFMA(aB1, B1, c1);
            const f4v dB2 = MFMA(aB0, B2, c2); const f4v eB2 = MFMA(aB1, B2, c2);
            const f4v dB3 = MFMA(aB0, B3, c3); const f4v eB3 = MFMA(aB1, B3, c3);
            #pragma unroll
            for (int q = 0; q < 4; ++q) {
                sA0[q] += fmaxf(dA0[q], 0.f) + fmaxf(eA0[q], 0.f);
                sA1[q] += fmaxf(dA1[q], 0.f) + fmaxf(eA1[q], 0.f);
                sA2[q] += fmaxf(dA2[q], 0.f) + fmaxf(eA2[q], 0.f);
                sA3[q] += fmaxf(dA3[q], 0.f) + fmaxf(eA3[q], 0.f);
                sB0[q] += fmaxf(dB0[q], 0.f) + fmaxf(eB0[q], 0.f);
                sB1[q] += fmaxf(dB1[q], 0.f) + fmaxf(eB1[q], 0.f);
                sB2[q] += fmaxf(dB2[q], 0.f) + fmaxf(eB2[q], 0.f);
                sB3[q] += fmaxf(dB3[q], 0.f) + fmaxf(eB3[q], 0.f);
            }
        }
        #pragma unroll
        for (int q = 0; q < 4; ++q) {
            const int e = 4 * g + q;
            const int m = (e & 7) << 3;
            W[1024 + e*64 + (( 0 + r) ^ m)] = (_Float16)sA0[q];
            W[1024 + e*64 + ((16 + r) ^ m)] = (_Float16)sA1[q];
            W[1024 + e*64 + ((32 + r) ^ m)] = (_Float16)sA2[q];
            W[1024 + e*64 + ((48 + r) ^ m)] = (_Float16)sA3[q];
            W[3136 + 1024 + e*64 + (( 0 + r) ^ m)] = (_Float16)sB0[q];
            W[3136 + 1024 + e*64 + ((16 + r) ^ m)] = (_Float16)sB1[q];
            W[3136 + 1024 + e*64 + ((32 + r) ^ m)] = (_Float16)sB2[q];
            W[3136 + 1024 + e*64 + ((48 + r) ^ m)] = (_Float16)sB3[q];
        }
    }

    // ================= C: pn = sn @ pnW2 + 16*pnb2 -> PN ======================
    {
        h8v b0 = FB[256 + 0*64 + l];
        h8v b1 = FB[256 + 1*64 + l];
        const float bb = 16.f * pnb2[r];
        const f4v c = {bb, bb, bb, bb};
        #pragma unroll
        for (int s = 0; s < 2; ++s) {
            _Float16* Ws_ = W + s * 3136;
            h8v a0 = *(const h8v*)&Ws_[r*64 + (( 0 + 8*g) ^ sw8)];
            h8v a1 = *(const h8v*)&Ws_[r*64 + ((32 + 8*g) ^ sw8)];
            f4v d = MFMA(a1, b1, MFMA(a0, b0, c));
            #pragma unroll
            for (int q = 0; q < 4; ++q) {
                const int row = 4 * g + q;
                Ws_[2048 + row*32 + (r ^ ((row&3)<<3))] = (_Float16)d[q];
            }
        }
    }
    // ================= D1: t = relu(pn @ rnW1 + rnb1) -> POOL =================
    {
        #pragma unroll
        for (int nt = 0; nt < 4; ++nt) {
            h8v b = FB[384 + nt*64 + l];
            const float bb = rnb1[16*nt + r];
            const f4v c = {bb, bb, bb, bb};
            #pragma unroll
            for (int s = 0; s < 2; ++s) {
                _Float16* Ws_ = W + s * 3136;
                h8v a = *(const h8v*)&Ws_[2048 + r*32 + ((8*g) ^ sw4)];
                f4v d = MFMA(a, b, c);
                #pragma unroll
                for (int q = 0; q < 4; ++q) {
                    const int row = 4 * g + q;
                    Ws_[row*64 + ((16*nt + r) ^ ((row&7)<<3))] = (_Float16)fmaxf(d[q], 0.f);
                }
            }
        }
    }
    // ================= D2: rn = t @ rnW2 + rnb2 -> HB cols 0..7 ===============
    {
        h8v b0 = FB[640 + 0*64 + l];
        h8v b1 = FB[640 + 1*64 + l];
        const float bb = (r < 8) ? rnb2[r & 7] : 0.f;
        const f4v c = {bb, bb, bb, bb};
        #pragma unroll
        for (int s = 0; s < 2; ++s) {
            _Float16* Ws_ = W + s * 3136;
            h8v a0 = *(const h8v*)&Ws_[r*64 + (( 0 + 8*g) ^ sw8)];
            h8v a1 = *(const h8v*)&Ws_[r*64 + ((32 + 8*g) ^ sw8)];
            f4v d = MFMA(a1, b1, MFMA(a0, b0, c));
            if (r < 8) {
                #pragma unroll
                for (int q = 0; q < 4; ++q) {
                    const int row = 4 * g + q;
                    Ws_[2560 + row*32 + (r ^ ((row&3)<<3))] = (_Float16)d[q];
                }
            }
        }
    }
    // ================= C': po = so @ poW2 + 32*pob2 -> PN =====================
    {
        h8v b0 = FB[1024 + 0*64 + l];
        h8v b1 = FB[1024 + 1*64 + l];
        const float bb = 32.f * pob2[r];
        const f4v c = {bb, bb, bb, bb};
        #pragma unroll
        for (int s = 0; s < 2; ++s) {
            _Float16* Ws_ = W + s * 3136;
            h8v a0 = *(const h8v*)&Ws_[1024 + r*64 + (( 0 + 8*g) ^ sw8)];
            h8v a1 = *(const h8v*)&Ws_[1024 + r*64 + ((32 + 8*g) ^ sw8)];
            f4v d = MFMA(a1, b1, MFMA(a0, b0, c));
            #pragma unroll
            for (int q = 0; q < 4; ++q) {
                const int row = 4 * g + q;
                Ws_[2048 + row*32 + (r ^ ((row&3)<<3))] = (_Float16)d[q];
            }
        }
    }
    // ================= D1': t2 = relu(po @ roW1 + rob1) -> POOL ===============
    {
        #pragma unroll
        for (int nt = 0; nt < 4; ++nt) {
            h8v b = FB[1152 + nt*64 + l];
            const float bb = rob1[16*nt + r];
            const f4v c = {bb, bb, bb, bb};
            #pragma unroll
            for (int s = 0; s < 2; ++s) {
                _Float16* Ws_ = W + s * 3136;
                h8v a = *(const h8v*)&Ws_[2048 + r*32 + ((8*g) ^ sw4)];
                f4v d = MFMA(a, b, c);
                #pragma unroll
                for (int q = 0; q < 4; ++q) {
                    const int row = 4 * g + q;
                    Ws_[row*64 + ((16*nt + r) ^ ((row&7)<<3))] = (_Float16)fmaxf(d[q], 0.f);
                }
            }
        }
    }
    // ================= D2': ro = t2 @ roW2 + rob2 -> HB cols 8..15 ============
    {
        h8v b0 = FB[1408 + 0*64 + l];
        h8v b1 = FB[1408 + 1*64 + l];
        const float bb = (r < 8) ? rob2[r & 7] : 0.f;
        const f4v c = {bb, bb, bb, bb};
        #pragma unroll
        for (int s = 0; s < 2; ++s) {
            _Float16* Ws_ = W + s * 3136;
            h8v a0 = *(const h8v*)&Ws_[r*64 + (( 0 + 8*g) ^ sw8)];
            h8v a1 = *(const h8v*)&Ws_[r*64 + ((32 + 8*g) ^ sw8)];
            f4v d = MFMA(a1, b1, MFMA(a0, b0, c));
            if (r < 8) {
                #pragma unroll
                for (int q = 0; q < 4; ++q) {
                    const int row = 4 * g + q;
                    Ws_[2560 + row*32 + ((8 + r) ^ ((row&3)<<3))] = (_Float16)d[q];
                }
            }
        }
    }
    // ================= F: ha = relu(h @ psW1 + psb1) -> TBUF ==================
    {
        #pragma unroll
        for (int nt = 0; nt < 4; ++nt) {
            h8v b = FB[1536 + nt*64 + l];
            const float bb = psb1[16*nt + r];
            const f4v c = {bb, bb, bb, bb};
            #pragma unroll
            for (int s = 0; s < 2; ++s) {
                _Float16* Ws_ = W + s * 3136;
                h8v a = *(const h8v*)&Ws_[2560 + r*32 + ((8*g) ^ sw4)];
                f4v d = MFMA(a, b, c);
                #pragma unroll
                for (int q = 0; q < 4; ++q) {
                    const int row = 4 * g + q;
                    Ws_[1024 + row*64 + ((16*nt + r) ^ ((row&7)<<3))] = (_Float16)fmaxf(d[q], 0.f);
                }
            }
        }
    }
    // ================= G1: t2 = relu(ha @ psW2 + psb2) -> POOL ================
    {
        #pragma unroll
        for (int nt = 0; nt < 4; ++nt) {
            h8v b0 = FB[1792 + (0*4 + nt)*64 + l];
            h8v b1 = FB[1792 + (1*4 + nt)*64 + l];
            const float bb = psb2[16*nt + r];
            const f4v c = {bb, bb, bb, bb};
            #pragma unroll
            for (int s = 0; s < 2; ++s) {
                _Float16* Ws_ = W + s * 3136;
                h8v a0 = *(const h8v*)&Ws_[1024 + r*64 + (( 0 + 8*g) ^ sw8)];
                h8v a1 = *(const h8v*)&Ws_[1024 + r*64 + ((32 + 8*g) ^ sw8)];
                f4v d = MFMA(a1, b1, MFMA(a0, b0, c));
                #pragma unroll
                for (int q = 0; q < 4; ++q) {
                    const int row = 4 * g + q;
                    Ws_[row*64 + ((16*nt + r) ^ ((row&7)<<3))] = (_Float16)fmaxf(d[q], 0.f);
                }
            }
        }
    }
    // ================= G2 + finale ============================================
    {
        h8v b0 = FB[2304 + 0*64 + l];
        h8v b1 = FB[2304 + 1*64 + l];
        const float bb = (r < 2) ? psb3[r & 1] : 0.f;
        const f4v c = {bb, bb, bb, bb};
        #pragma unroll
        for (int s = 0; s < 2; ++s) {
            _Float16* Ws_ = W + s * 3136;
            const float* barf = (const float*)(Ws_ + 3072);
            h8v a0 = *(const h8v*)&Ws_[r*64 + (( 0 + 8*g) ^ sw8)];
            h8v a1 = *(const h8v*)&Ws_[r*64 + ((32 + 8*g) ^ sw8)];
            f4v dOut = MFMA(a1, b1, MFMA(a0, b0, c));
            if (r < 2) {
                #pragma unroll
                for (int q = 0; q < 4; ++q) {
                    const int e = 4 * g + q;
                    const float o = dOut[q];
                    const float bar = barf[e*2 + r];
                    const float nz = noise[2 * (size_t)(eb + 16*s + e) + r];
                    const float av = tanhf(2.f * tanhf(o) + bar + nz);
                    out[2 * (size_t)(eb + 16*s + e) + r] = 2.f * av;
                }
            }
        }
    }
}

extern "C" void kernel_launch(void* const* d_in, const int* in_sizes, int n_in,
                              void* d_out, int out_size, void* d_ws, size_t ws_size,
                              hipStream_t stream) {
    const float* x    = (const float*)d_in[0];
    const float* nz   = (const float*)d_in[1];
    const float* pnW1 = (const float*)d_in[2];
    const float* pnb1 = (const float*)d_in[3];
    const float* pnW2 = (const float*)d_in[4];
    const float* pnb2 = (const float*)d_in[5];
    const float* rnW1 = (const float*)d_in[6];
    const float* rnb1 = (const float*)d_in[7];
    const float* rnW2 = (const float*)d_in[8];
    const float* rnb2 = (const float*)d_in[9];
    const float* poW1 = (const float*)d_in[10];
    const float* pob1 = (const float*)d_in[11];
    const float* poW2 = (const float*)d_in[12];
    const float* pob2 = (const float*)d_in[13];
    const float* roW1 = (const float*)d_in[14];
    const float* rob1 = (const float*)d_in[15];
    const float* roW2 = (const float*)d_in[16];
    const float* rob2 = (const float*)d_in[17];
    const float* psW1 = (const float*)d_in[18];
    const float* psb1 = (const float*)d_in[19];
    const float* psW2 = (const float*)d_in[20];
    const float* psb2 = (const float*)d_in[21];
    const float* psW3 = (const float*)d_in[22];
    const float* psb3 = (const float*)d_in[23];

    unsigned* ws = (unsigned*)d_ws;
    hipLaunchKernelGGL(prep_frags, dim3(38), dim3(256), 0, stream,
        pnW1, pnW2, rnW1, rnW2, poW1, poW2, roW1, roW2, psW1, psW2, psW3, ws);

    const int b = in_sizes[0] / XCOLS;
    hipLaunchKernelGGL(barrier_net_kernel, dim3(b / 32), dim3(64), 0, stream,
        x, nz, pnb1, pnb2, rnb1, rnb2, pob1, pob2, rob1, rob2,
        psb1, psb2, psb3, ws, (float*)d_out);
}

// Round 13
// 48.957 us; speedup vs baseline: 1.2037x; 1.2037x over previous
//
#include <hip/hip_runtime.h>

#define NN 16
#define NO 32
#define XCOLS 133

typedef _Float16 h8v __attribute__((ext_vector_type(8)));
typedef _Float16 h2 __attribute__((ext_vector_type(2)));
typedef float f4v __attribute__((ext_vector_type(4)));
typedef unsigned ui4 __attribute__((ext_vector_type(4)));
typedef float f2u __attribute__((ext_vector_type(2), aligned(4)));

static __device__ __forceinline__ f4v MFMA(h8v a, h8v b, f4v c) {
    return __builtin_amdgcn_mfma_f32_16x16x32_f16(a, b, c, 0, 0, 0);
}
static __device__ __forceinline__ unsigned pkbits(float a, float b) {
    return __builtin_bit_cast(unsigned, __builtin_amdgcn_cvt_pkrtz(a, b));
}
static __device__ __forceinline__ h2 u2h(unsigned v) { return __builtin_bit_cast(h2, v); }

// ---------------------------------------------------------------------------
// prep (parallel, verified): pack weights into MFMA B-fragment arrays.
// B[k][col]: col = 16*nt + (lane&15), k = 32*kc + 8*(lane>>4) + j; zero-padded.
// ---------------------------------------------------------------------------
__global__ void prep_frags(
    const float* __restrict__ pnW1, const float* __restrict__ pnW2,
    const float* __restrict__ rnW1, const float* __restrict__ rnW2,
    const float* __restrict__ poW1, const float* __restrict__ poW2,
    const float* __restrict__ roW1, const float* __restrict__ roW2,
    const float* __restrict__ psW1, const float* __restrict__ psW2,
    const float* __restrict__ psW3, unsigned* __restrict__ ws)
{
    const float* Ws[11] = {pnW1,pnW2,rnW1,rnW2,poW1,poW2,roW1,roW2,psW1,psW2,psW3};
    const int Kr[11]   = {4,64,16,64,2,64,16,64,18,64,64};
    const int Nr[11]   = {64,16,64,8,64,16,64,8,64,64,2};
    const int nkc[11]  = {1,2,1,2,1,2,1,2,1,2,2};
    const int nnt[11]  = {4,1,4,1,4,1,4,1,4,4,1};
    const int base[11] = {0,1024,1536,2560,3072,4096,4608,5632,6144,7168,9216};

    const int gid = blockIdx.x * 256 + threadIdx.x;   // 0..9727
    int start = 0;
    #pragma unroll
    for (int a2 = 0; a2 < 11; ++a2) {
        const int n = nkc[a2] * nnt[a2] * 256;
        if (gid >= start && gid < start + n) {
            const int i = gid - start;
            const float* Wm = Ws[a2];
            const int K = Kr[a2], N = Nr[a2], nt_n = nnt[a2];
            const int d = i & 3, lane = (i >> 2) & 63, t = i >> 8;
            const int nt = t % nt_n, kc = t / nt_n;
            const int k = kc * 32 + 8 * (lane >> 4) + 2 * d;
            const int col = nt * 16 + (lane & 15);
            const float v0 = (k     < K && col < N) ? Wm[(k    ) * N + col] : 0.f;
            const float v1 = (k + 1 < K && col < N) ? Wm[(k + 1) * N + col] : 0.f;
            ws[base[a2] + i] = pkbits(v0, v1);
        }
        start += n;
    }
}

// ---------------------------------------------------------------------------
// main: 128-thread blocks = 2 COOPERATING waves per 16 elements. Work split
// (total-work-invariant TLP doubling vs R11):
//   L1n/L1o: wave w computes feature col-tiles {2w,2w+1} over ALL points
//            (disjoint column halves of shared pool buffers -> no combine).
//   dense:   w0 = N-branch (C,D1,D2); w1 = O-branch (C',D1',D2').
//   F/G1:    split by nt col-tiles (2 each). G2+finale: w0.
// LDS (f16 idx): sn@0[16][64] (->tN->ha), so@1024[16][64] (->tO->t2),
// PNn@2048[16][32], PNo@2560[16][32], HB@3072[16][32], barfA@3584(32f32),
// barfB@3648, XS dwords @3712 (16 rows x 66). Total 5824 f16 = 11648 B.
// ---------------------------------------------------------------------------
#define SN  0
#define SO  1024
#define PNN 2048
#define PNO 2560
#define HBF 3072
#define BARA 3584
#define BARB 3648
#define XSF 3712

__global__ __launch_bounds__(128, 8) void barrier_net_kernel(
    const float* __restrict__ x, const float* __restrict__ noise,
    const float* __restrict__ pnb1, const float* __restrict__ pnb2,
    const float* __restrict__ rnb1, const float* __restrict__ rnb2,
    const float* __restrict__ pob1, const float* __restrict__ pob2,
    const float* __restrict__ rob1, const float* __restrict__ rob2,
    const float* __restrict__ psb1, const float* __restrict__ psb2,
    const float* __restrict__ psb3,
    const unsigned* __restrict__ wsu, float* __restrict__ out)
{
    __shared__ _Float16 S[5824];
    unsigned* XS = (unsigned*)S + (XSF / 2);
    float* barfA = (float*)(S + BARA);
    float* barfB = (float*)(S + BARB);

    const int tid = threadIdx.x;     // 0..127
    const int l = tid & 63;
    const int w = tid >> 6;          // wave 0/1
    const int r = l & 15;
    const int g = l >> 4;
    const int eb = blockIdx.x * 16;

    const h8v* FB = (const h8v*)wsu;
    const int sw8 = (r & 7) << 3;
    const int sw4 = (r & 3) << 3;
    const int nt0 = 2 * w, nt1 = 2 * w + 1;

    {   // zero PNn/PNo/HB (768 dwords over 128 threads)
        unsigned* z = (unsigned*)(S + PNN);
        #pragma unroll
        for (int i = 0; i < 6; ++i) z[tid + 128 * i] = 0u;
    }
    {   // stage x rows (cols 5..132 as f16 pairs) + goal (cols 1,2)
        const float* base = x + (size_t)eb * XCOLS;
        f2u raw[8];
        #pragma unroll
        for (int i = 0; i < 8; ++i) {
            const int idx = i * 128 + tid;
            const int ee = idx >> 6, cp = idx & 63;
            raw[i] = *(const f2u*)(base + (size_t)ee * XCOLS + 5 + 2 * cp);
        }
        #pragma unroll
        for (int i = 0; i < 8; ++i) {
            const int idx = i * 128 + tid;
            const int ee = idx >> 6, cp = idx & 63;
            XS[ee * 66 + cp] = pkbits(raw[i][0], raw[i][1]);
        }
        if (tid < 16) {
            const f2u graw = *(const f2u*)(base + (size_t)tid * XCOLS + 1);
            XS[tid * 66 + 64] = pkbits(graw[0], graw[1]);
        }
    }
    __syncthreads();  // B1: XS + zeros visible

    const int rowb = r * 66;

    // ---- goal cols 16,17 -> HB (w0 lanes g==0)
    if (tid < 16) {
        const h2 gv = u2h(XS[tid * 66 + 64]);
        const int m = (tid & 3) << 3;
        S[HBF + tid * 32 + (16 ^ m)] = gv[0];
        S[HBF + tid * 32 + (17 ^ m)] = gv[1];
    }

    // ---- barrier pass: wave w handles its point half, partial to barfA/B
    {
        float bq0 = 0.f, bq1 = 0.f;
        #pragma unroll
        for (int jj = 0; jj < 2; ++jj) {               // neighbors: 8w+2g+jj
            const h2 v = u2h(XS[rowb + 2 * (8 * w + 2 * g + jj)]);
            const float v0 = (float)v[0], v1 = (float)v[1];
            const float nrm = sqrtf(v0*v0 + v1*v1);
            const float cc = 0.01f * __builtin_amdgcn_rcpf(nrm * (nrm - 0.3f));
            bq0 -= cc * v0; bq1 -= cc * v1;
        }
        #pragma unroll
        for (int jj = 0; jj < 4; ++jj) {               // obstacles: 16w+4g+jj
            const h2 v = u2h(XS[rowb + 32 + 16 * w + 4 * g + jj]);
            const float v0 = (float)v[0], v1 = (float)v[1];
            const float nrm = sqrtf(v0*v0 + v1*v1);
            const float cc = 0.01f * __builtin_amdgcn_rcpf(nrm * (nrm - 0.5f));
            bq0 -= cc * v0; bq1 -= cc * v1;
        }
        bq0 += __shfl_xor(bq0, 16); bq0 += __shfl_xor(bq0, 32);
        bq1 += __shfl_xor(bq1, 16); bq1 += __shfl_xor(bq1, 32);
        if (g == 0) {
            float* bf = w ? barfB : barfA;
            bf[2*r] = bq0; bf[2*r + 1] = bq1;
        }
    }

    // ---- L1 neighbor: col-tiles nt0,nt1 over all 16 points
    {
        const h8v B0 = FB[nt0 * 64 + l], B1 = FB[nt1 * 64 + l];
        const float b0s = pnb1[16*nt0 + r], b1s = pnb1[16*nt1 + r];
        const f4v c0 = {b0s, b0s, b0s, b0s};
        const f4v c1 = {b1s, b1s, b1s, b1s};
        f4v s0 = {0,0,0,0}, s1 = {0,0,0,0};
        #pragma unroll 4
        for (int j = 0; j < NN; ++j) {
            const uint2 np = *(const uint2*)&XS[rowb + 2 * j];
            ui4 au = {np.x, np.y, 0u, 0u};
            const h8v a = __builtin_bit_cast(h8v, au);
            const f4v d0 = MFMA(a, B0, c0);
            const f4v d1 = MFMA(a, B1, c1);
            #pragma unroll
            for (int q = 0; q < 4; ++q) {
                s0[q] += fmaxf(d0[q], 0.f);
                s1[q] += fmaxf(d1[q], 0.f);
            }
        }
        #pragma unroll
        for (int q = 0; q < 4; ++q) {
            const int e = 4 * g + q;
            const int m = (e & 7) << 3;
            S[SN + e*64 + ((16*nt0 + r) ^ m)] = (_Float16)s0[q];
            S[SN + e*64 + ((16*nt1 + r) ^ m)] = (_Float16)s1[q];
        }
    }

    // ---- L1 obstacle: col-tiles nt0,nt1 over all 32 points (2/iter)
    {
        const h8v B0 = FB[768 + nt0 * 64 + l], B1 = FB[768 + nt1 * 64 + l];
        const float b0s = pob1[16*nt0 + r], b1s = pob1[16*nt1 + r];
        const f4v c0 = {b0s, b0s, b0s, b0s};
        const f4v c1 = {b1s, b1s, b1s, b1s};
        f4v s0 = {0,0,0,0}, s1 = {0,0,0,0};
        #pragma unroll 2
        for (int t = 0; t < 16; ++t) {
            const uint2 op = *(const uint2*)&XS[rowb + 32 + 2 * t];
            ui4 a0u = {op.x, 0u, 0u, 0u};
            ui4 a1u = {op.y, 0u, 0u, 0u};
            const h8v a0 = __builtin_bit_cast(h8v, a0u);
            const h8v a1 = __builtin_bit_cast(h8v, a1u);
            const f4v d0 = MFMA(a0, B0, c0); const f4v e0 = MFMA(a1, B0, c0);
            const f4v d1 = MFMA(a0, B1, c1); const f4v e1 = MFMA(a1, B1, c1);
            #pragma unroll
            for (int q = 0; q < 4; ++q) {
                s0[q] += fmaxf(d0[q], 0.f) + fmaxf(e0[q], 0.f);
                s1[q] += fmaxf(d1[q], 0.f) + fmaxf(e1[q], 0.f);
            }
        }
        #pragma unroll
        for (int q = 0; q < 4; ++q) {
            const int e = 4 * g + q;
            const int m = (e & 7) << 3;
            S[SO + e*64 + ((16*nt0 + r) ^ m)] = (_Float16)s0[q];
            S[SO + e*64 + ((16*nt1 + r) ^ m)] = (_Float16)s1[q];
        }
    }
    __syncthreads();  // B2: pools complete

    // ---- branch stages: w0 = N-chain, w1 = O-chain
    if (w == 0) {
        // C: pn = sn @ pnW2 + 16*pnb2 -> PNn
        {
            h8v a0 = *(const h8v*)&S[SN + r*64 + (( 0 + 8*g) ^ sw8)];
            h8v a1 = *(const h8v*)&S[SN + r*64 + ((32 + 8*g) ^ sw8)];
            h8v b0 = FB[256 + 0*64 + l];
            h8v b1 = FB[256 + 1*64 + l];
            const float bb = 16.f * pnb2[r];
            f4v c = {bb, bb, bb, bb};
            f4v d = MFMA(a1, b1, MFMA(a0, b0, c));
            #pragma unroll
            for (int q = 0; q < 4; ++q) {
                const int row = 4 * g + q;
                S[PNN + row*32 + (r ^ ((row&3)<<3))] = (_Float16)d[q];
            }
        }
        // D1: tN = relu(pn @ rnW1 + rnb1) -> over sn region
        {
            h8v a = *(const h8v*)&S[PNN + r*32 + ((8*g) ^ sw4)];
            #pragma unroll
            for (int nt = 0; nt < 4; ++nt) {
                h8v b = FB[384 + nt*64 + l];
                const float bb = rnb1[16*nt + r];
                f4v c = {bb, bb, bb, bb};
                f4v d = MFMA(a, b, c);
                #pragma unroll
                for (int q = 0; q < 4; ++q) {
                    const int row = 4 * g + q;
                    S[SN + row*64 + ((16*nt + r) ^ ((row&7)<<3))] = (_Float16)fmaxf(d[q], 0.f);
                }
            }
        }
        // D2: rn = tN @ rnW2 + rnb2 -> HB cols 0..7
        {
            h8v a0 = *(const h8v*)&S[SN + r*64 + (( 0 + 8*g) ^ sw8)];
            h8v a1 = *(const h8v*)&S[SN + r*64 + ((32 + 8*g) ^ sw8)];
            h8v b0 = FB[640 + 0*64 + l];
            h8v b1 = FB[640 + 1*64 + l];
            const float bb = (r < 8) ? rnb2[r & 7] : 0.f;
            f4v c = {bb, bb, bb, bb};
            f4v d = MFMA(a1, b1, MFMA(a0, b0, c));
            if (r < 8) {
                #pragma unroll
                for (int q = 0; q < 4; ++q) {
                    const int row = 4 * g + q;
                    S[HBF + row*32 + (r ^ ((row&3)<<3))] = (_Float16)d[q];
                }
            }
        }
    } else {
        // C': po = so @ poW2 + 32*pob2 -> PNo
        {
            h8v a0 = *(const h8v*)&S[SO + r*64 + (( 0 + 8*g) ^ sw8)];
            h8v a1 = *(const h8v*)&S[SO + r*64 + ((32 + 8*g) ^ sw8)];
            h8v b0 = FB[1024 + 0*64 + l];
            h8v b1 = FB[1024 + 1*64 + l];
            const float bb = 32.f * pob2[r];
            f4v c = {bb, bb, bb, bb};
            f4v d = MFMA(a1, b1, MFMA(a0, b0, c));
            #pragma unroll
            for (int q = 0; q < 4; ++q) {
                const int row = 4 * g + q;
                S[PNO + row*32 + (r ^ ((row&3)<<3))] = (_Float16)d[q];
            }
        }
        // D1': tO = relu(po @ roW1 + rob1) -> over so region
        {
            h8v a = *(const h8v*)&S[PNO + r*32 + ((8*g) ^ sw4)];
            #pragma unroll
            for (int nt = 0; nt < 4; ++nt) {
                h8v b = FB[1152 + nt*64 + l];
                const float bb = rob1[16*nt + r];
                f4v c = {bb, bb, bb, bb};
                f4v d = MFMA(a, b, c);
                #pragma unroll
                for (int q = 0; q < 4; ++q) {
                    const int row = 4 * g + q;
                    S[SO + row*64 + ((16*nt + r) ^ ((row&7)<<3))] = (_Float16)fmaxf(d[q], 0.f);
                }
            }
        }
        // D2': ro = tO @ roW2 + rob2 -> HB cols 8..15
        {
            h8v a0 = *(const h8v*)&S[SO + r*64 + (( 0 + 8*g) ^ sw8)];
            h8v a1 = *(const h8v*)&S[SO + r*64 + ((32 + 8*g) ^ sw8)];
            h8v b0 = FB[1408 + 0*64 + l];
            h8v b1 = FB[1408 + 1*64 + l];
            const float bb = (r < 8) ? rob2[r & 7] : 0.f;
            f4v c = {bb, bb, bb, bb};
            f4v d = MFMA(a1, b1, MFMA(a0, b0, c));
            if (r < 8) {
                #pragma unroll
                for (int q = 0; q < 4; ++q) {
                    const int row = 4 * g + q;
                    S[HBF + row*32 + ((8 + r) ^ ((row&3)<<3))] = (_Float16)d[q];
                }
            }
        }
    }
    __syncthreads();  // B3: HB complete (rn | ro | goal)

    // ---- F: ha = relu(h @ psW1 + psb1); wave w writes col-tiles nt0,nt1 -> sn region
    {
        h8v a = *(const h8v*)&S[HBF + r*32 + ((8*g) ^ sw4)];
        h8v b0 = FB[1536 + nt0*64 + l];
        h8v b1 = FB[1536 + nt1*64 + l];
        const float b0s = psb1[16*nt0 + r], b1s = psb1[16*nt1 + r];
        f4v c0 = {b0s, b0s, b0s, b0s};
        f4v c1 = {b1s, b1s, b1s, b1s};
        f4v d0 = MFMA(a, b0, c0);
        f4v d1 = MFMA(a, b1, c1);
        #pragma unroll
        for (int q = 0; q < 4; ++q) {
            const int row = 4 * g + q;
            const int m = (row & 7) << 3;
            S[SN + row*64 + ((16*nt0 + r) ^ m)] = (_Float16)fmaxf(d0[q], 0.f);
            S[SN + row*64 + ((16*nt1 + r) ^ m)] = (_Float16)fmaxf(d1[q], 0.f);
        }
    }
    __syncthreads();  // B4: ha complete

    // ---- G1: t2 = relu(ha @ psW2 + psb2); wave w writes nt0,nt1 -> so region
    {
        h8v a0 = *(const h8v*)&S[SN + r*64 + (( 0 + 8*g) ^ sw8)];
        h8v a1 = *(const h8v*)&S[SN + r*64 + ((32 + 8*g) ^ sw8)];
        #pragma unroll
        for (int i = 0; i < 2; ++i) {
            const int nt = 2 * w + i;
            h8v b0 = FB[1792 + (0*4 + nt)*64 + l];
            h8v b1 = FB[1792 + (1*4 + nt)*64 + l];
            const float bb = psb2[16*nt + r];
            f4v c = {bb, bb, bb, bb};
            f4v d = MFMA(a1, b1, MFMA(a0, b0, c));
            #pragma unroll
            for (int q = 0; q < 4; ++q) {
                const int row = 4 * g + q;
                S[SO + row*64 + ((16*nt + r) ^ ((row&7)<<3))] = (_Float16)fmaxf(d[q], 0.f);
            }
        }
    }
    __syncthreads();  // B5: t2 complete

    // ---- G2 + finale (w0)
    if (w == 0) {
        h8v a0 = *(const h8v*)&S[SO + r*64 + (( 0 + 8*g) ^ sw8)];
        h8v a1 = *(const h8v*)&S[SO + r*64 + ((32 + 8*g) ^ sw8)];
        h8v b0 = FB[2304 + 0*64 + l];
        h8v b1 = FB[2304 + 1*64 + l];
        const float bb = (r < 2) ? psb3[r & 1] : 0.f;
        f4v c = {bb, bb, bb, bb};
        f4v dOut = MFMA(a1, b1, MFMA(a0, b0, c));
        if (r < 2) {
            #pragma unroll
            for (int q = 0; q < 4; ++q) {
                const int e = 4 * g + q;
                const float o = dOut[q];
                const float bar = barfA[e*2 + r] + barfB[e*2 + r];
                const float nz = noise[2 * (size_t)(eb + e) + r];
                const float av = tanhf(2.f * tanhf(o) + bar + nz);
                out[2 * (size_t)(eb + e) + r] = 2.f * av;
            }
        }
    }
}

extern "C" void kernel_launch(void* const* d_in, const int* in_sizes, int n_in,
                              void* d_out, int out_size, void* d_ws, size_t ws_size,
                              hipStream_t stream) {
    const float* x    = (const float*)d_in[0];
    const float* nz   = (const float*)d_in[1];
    const float* pnW1 = (const float*)d_in[2];
    const float* pnb1 = (const float*)d_in[3];
    const float* pnW2 = (const float*)d_in[4];
    const float* pnb2 = (const float*)d_in[5];
    const float* rnW1 = (const float*)d_in[6];
    const float* rnb1 = (const float*)d_in[7];
    const float* rnW2 = (const float*)d_in[8];
    const float* rnb2 = (const float*)d_in[9];
    const float* poW1 = (const float*)d_in[10];
    const float* pob1 = (const float*)d_in[11];
    const float* poW2 = (const float*)d_in[12];
    const float* pob2 = (const float*)d_in[13];
    const float* roW1 = (const float*)d_in[14];
    const float* rob1 = (const float*)d_in[15];
    const float* roW2 = (const float*)d_in[16];
    const float* rob2 = (const float*)d_in[17];
    const float* psW1 = (const float*)d_in[18];
    const float* psb1 = (const float*)d_in[19];
    const float* psW2 = (const float*)d_in[20];
    const float* psb2 = (const float*)d_in[21];
    const float* psW3 = (const float*)d_in[22];
    const float* psb3 = (const float*)d_in[23];

    unsigned* ws = (unsigned*)d_ws;
    hipLaunchKernelGGL(prep_frags, dim3(38), dim3(256), 0, stream,
        pnW1, pnW2, rnW1, rnW2, poW1, poW2, roW1, roW2, psW1, psW2, psW3, ws);

    const int b = in_sizes[0] / XCOLS;
    hipLaunchKernelGGL(barrier_net_kernel, dim3(b / 16), dim3(128), 0, stream,
        x, nz, pnb1, pnb2, rnb1, rnb2, pob1, pob2, rob1, rob2,
        psb1, psb2, psb3, ws, (float*)d_out);
}

// Round 15
// 45.971 us; speedup vs baseline: 1.2819x; 1.0649x over previous
//
#include <hip/hip_runtime.h>

#define NN 16
#define NO 32
#define XCOLS 133

typedef _Float16 h8v __attribute__((ext_vector_type(8)));
typedef _Float16 h2 __attribute__((ext_vector_type(2)));
typedef float f4v __attribute__((ext_vector_type(4)));
typedef unsigned ui4 __attribute__((ext_vector_type(4)));
typedef float f2u __attribute__((ext_vector_type(2), aligned(4)));

static __device__ __forceinline__ f4v MFMA(h8v a, h8v b, f4v c) {
    return __builtin_amdgcn_mfma_f32_16x16x32_f16(a, b, c, 0, 0, 0);
}
static __device__ __forceinline__ unsigned pkbits(float a, float b) {
    return __builtin_bit_cast(unsigned, __builtin_amdgcn_cvt_pkrtz(a, b));
}
static __device__ __forceinline__ h2 u2h(unsigned v) { return __builtin_bit_cast(h2, v); }
static __device__ __forceinline__ void prio1() { __builtin_amdgcn_s_setprio(1); }
static __device__ __forceinline__ void prio0() { __builtin_amdgcn_s_setprio(0); }

// ---------------------------------------------------------------------------
// prep (parallel, verified): pack weights into MFMA B-fragment arrays.
// B[k][col]: col = 16*nt + (lane&15), k = 32*kc + 8*(lane>>4) + j; zero-padded.
// ---------------------------------------------------------------------------
__global__ void prep_frags(
    const float* __restrict__ pnW1, const float* __restrict__ pnW2,
    const float* __restrict__ rnW1, const float* __restrict__ rnW2,
    const float* __restrict__ poW1, const float* __restrict__ poW2,
    const float* __restrict__ roW1, const float* __restrict__ roW2,
    const float* __restrict__ psW1, const float* __restrict__ psW2,
    const float* __restrict__ psW3, unsigned* __restrict__ ws)
{
    const float* Ws[11] = {pnW1,pnW2,rnW1,rnW2,poW1,poW2,roW1,roW2,psW1,psW2,psW3};
    const int Kr[11]   = {4,64,16,64,2,64,16,64,18,64,64};
    const int Nr[11]   = {64,16,64,8,64,16,64,8,64,64,2};
    const int nkc[11]  = {1,2,1,2,1,2,1,2,1,2,2};
    const int nnt[11]  = {4,1,4,1,4,1,4,1,4,4,1};
    const int base[11] = {0,1024,1536,2560,3072,4096,4608,5632,6144,7168,9216};

    const int gid = blockIdx.x * 256 + threadIdx.x;   // 0..9727
    int start = 0;
    #pragma unroll
    for (int a2 = 0; a2 < 11; ++a2) {
        const int n = nkc[a2] * nnt[a2] * 256;
        if (gid >= start && gid < start + n) {
            const int i = gid - start;
            const float* Wm = Ws[a2];
            const int K = Kr[a2], N = Nr[a2], nt_n = nnt[a2];
            const int d = i & 3, lane = (i >> 2) & 63, t = i >> 8;
            const int nt = t % nt_n, kc = t / nt_n;
            const int k = kc * 32 + 8 * (lane >> 4) + 2 * d;
            const int col = nt * 16 + (lane & 15);
            const float v0 = (k     < K && col < N) ? Wm[(k    ) * N + col] : 0.f;
            const float v1 = (k + 1 < K && col < N) ? Wm[(k + 1) * N + col] : 0.f;
            ws[base[a2] + i] = pkbits(v0, v1);
        }
        start += n;
    }
}

// ---------------------------------------------------------------------------
// main: R11 structure (measured best, 42 µs dispatch): 64-thread (1-wave)
// blocks, 16 elements each; x burst-staged to XS[16][66]; L1 point-loops;
// dense chain via per-wave LDS. NEW vs R11: s_setprio(1) around every MFMA
// cluster — waves here are independent and phase-skewed (the attn-like regime
// where T5 measured +4-7%, m191).
// LDS: XS 4224B + W 6272B = 10496B.
// ---------------------------------------------------------------------------
__global__ __launch_bounds__(64, 4) void barrier_net_kernel(
    const float* __restrict__ x, const float* __restrict__ noise,
    const float* __restrict__ pnb1, const float* __restrict__ pnb2,
    const float* __restrict__ rnb1, const float* __restrict__ rnb2,
    const float* __restrict__ pob1, const float* __restrict__ pob2,
    const float* __restrict__ rob1, const float* __restrict__ rob2,
    const float* __restrict__ psb1, const float* __restrict__ psb2,
    const float* __restrict__ psb3,
    const unsigned* __restrict__ wsu, float* __restrict__ out)
{
    __shared__ unsigned XS[16 * 66];
    __shared__ _Float16 W[3136];       // POOL@0, TBUF@1024, PN@2048, HB@2560, barf@3072

    const int l = threadIdx.x;
    const int r = l & 15;
    const int g = l >> 4;
    const int eb = blockIdx.x * 16;

    float* barf = (float*)(W + 3072);
    const h8v* FB = (const h8v*)wsu;

    // ---- burst-stage x: 16 rows x 128 floats (cols 5..132) + goal (cols 1,2)
    {
        const float* base = x + (size_t)eb * XCOLS;
        f2u raw[16];
        #pragma unroll
        for (int it = 0; it < 16; ++it)
            raw[it] = *(const f2u*)(base + (size_t)it * XCOLS + 5 + 2 * l);
        f2u graw = {0.f, 0.f};
        if (l < 16) graw = *(const f2u*)(base + (size_t)l * XCOLS + 1);
        #pragma unroll
        for (int it = 0; it < 16; ++it)
            XS[it * 66 + l] = pkbits(raw[it][0], raw[it][1]);
        if (l < 16) XS[l * 66 + 64] = pkbits(graw[0], graw[1]);
    }

    {   // zero PN+HB (2048..3072 f16 = 512 dwords, 8/lane)
        unsigned* z = (unsigned*)(W + 2048);
        #pragma unroll
        for (int i = 0; i < 8; ++i) z[l + 64 * i] = 0u;
    }

    const int rowb = r * 66;
    const int sw8 = (r & 7) << 3;
    const int sw4 = (r & 3) << 3;

    // ================= barrier pass (dedup'd across g, from XS) ===============
    {
        float bq0 = 0.f, bq1 = 0.f;
        #pragma unroll
        for (int jj = 0; jj < 4; ++jj) {
            const h2 v = u2h(XS[rowb + 2 * (4 * g + jj)]);
            const float v0 = (float)v[0], v1 = (float)v[1];
            const float nrm = sqrtf(v0*v0 + v1*v1);
            const float cc = 0.01f * __builtin_amdgcn_rcpf(nrm * (nrm - 0.3f));
            bq0 -= cc * v0; bq1 -= cc * v1;
        }
        #pragma unroll
        for (int jj = 0; jj < 8; ++jj) {
            const h2 v = u2h(XS[rowb + 32 + 8 * g + jj]);
            const float v0 = (float)v[0], v1 = (float)v[1];
            const float nrm = sqrtf(v0*v0 + v1*v1);
            const float cc = 0.01f * __builtin_amdgcn_rcpf(nrm * (nrm - 0.5f));
            bq0 -= cc * v0; bq1 -= cc * v1;
        }
        bq0 += __shfl_xor(bq0, 16); bq0 += __shfl_xor(bq0, 32);
        bq1 += __shfl_xor(bq1, 16); bq1 += __shfl_xor(bq1, 32);
        if (g == 0) { barf[2*r] = bq0; barf[2*r + 1] = bq1; }
    }

    // ================= L1 neighbor: point-loop from XS ========================
    {
        const h8v B0 = FB[0*64 + l], B1 = FB[1*64 + l];
        const h8v B2 = FB[2*64 + l], B3 = FB[3*64 + l];
        const f4v c0 = {pnb1[r], pnb1[r], pnb1[r], pnb1[r]};
        const f4v c1 = {pnb1[16+r], pnb1[16+r], pnb1[16+r], pnb1[16+r]};
        const f4v c2 = {pnb1[32+r], pnb1[32+r], pnb1[32+r], pnb1[32+r]};
        const f4v c3 = {pnb1[48+r], pnb1[48+r], pnb1[48+r], pnb1[48+r]};
        f4v s0 = {0,0,0,0}, s1 = {0,0,0,0}, s2 = {0,0,0,0}, s3 = {0,0,0,0};
        #pragma unroll 4
        for (int j = 0; j < NN; ++j) {
            const uint2 np = *(const uint2*)&XS[rowb + 2 * j];
            ui4 au = {np.x, np.y, 0u, 0u};
            const h8v a = __builtin_bit_cast(h8v, au);
            prio1();
            const f4v d0 = MFMA(a, B0, c0);
            const f4v d1 = MFMA(a, B1, c1);
            const f4v d2 = MFMA(a, B2, c2);
            const f4v d3 = MFMA(a, B3, c3);
            prio0();
            #pragma unroll
            for (int q = 0; q < 4; ++q) {
                s0[q] += fmaxf(d0[q], 0.f); s1[q] += fmaxf(d1[q], 0.f);
                s2[q] += fmaxf(d2[q], 0.f); s3[q] += fmaxf(d3[q], 0.f);
            }
        }
        #pragma unroll
        for (int q = 0; q < 4; ++q) {
            const int e = 4 * g + q;
            const int m = (e & 7) << 3;
            W[e*64 + (( 0 + r) ^ m)] = (_Float16)s0[q];
            W[e*64 + ((16 + r) ^ m)] = (_Float16)s1[q];
            W[e*64 + ((32 + r) ^ m)] = (_Float16)s2[q];
            W[e*64 + ((48 + r) ^ m)] = (_Float16)s3[q];
        }
    }

    // ================= L1 obstacle: point-loop from XS, 2 pts/iter ============
    {
        const h8v B0 = FB[768 + 0*64 + l], B1 = FB[768 + 1*64 + l];
        const h8v B2 = FB[768 + 2*64 + l], B3 = FB[768 + 3*64 + l];
        const f4v c0 = {pob1[r], pob1[r], pob1[r], pob1[r]};
        const f4v c1 = {pob1[16+r], pob1[16+r], pob1[16+r], pob1[16+r]};
        const f4v c2 = {pob1[32+r], pob1[32+r], pob1[32+r], pob1[32+r]};
        const f4v c3 = {pob1[48+r], pob1[48+r], pob1[48+r], pob1[48+r]};
        f4v s0 = {0,0,0,0}, s1 = {0,0,0,0}, s2 = {0,0,0,0}, s3 = {0,0,0,0};
        #pragma unroll 2
        for (int t = 0; t < 16; ++t) {
            const uint2 op = *(const uint2*)&XS[rowb + 32 + 2 * t];
            ui4 au0 = {op.x, 0u, 0u, 0u};
            ui4 au1 = {op.y, 0u, 0u, 0u};
            const h8v a0 = __builtin_bit_cast(h8v, au0);
            const h8v a1 = __builtin_bit_cast(h8v, au1);
            prio1();
            const f4v d0 = MFMA(a0, B0, c0); const f4v e0 = MFMA(a1, B0, c0);
            const f4v d1 = MFMA(a0, B1, c1); const f4v e1 = MFMA(a1, B1, c1);
            const f4v d2 = MFMA(a0, B2, c2); const f4v e2 = MFMA(a1, B2, c2);
            const f4v d3 = MFMA(a0, B3, c3); const f4v e3 = MFMA(a1, B3, c3);
            prio0();
            #pragma unroll
            for (int q = 0; q < 4; ++q) {
                s0[q] += fmaxf(d0[q], 0.f) + fmaxf(e0[q], 0.f);
                s1[q] += fmaxf(d1[q], 0.f) + fmaxf(e1[q], 0.f);
                s2[q] += fmaxf(d2[q], 0.f) + fmaxf(e2[q], 0.f);
                s3[q] += fmaxf(d3[q], 0.f) + fmaxf(e3[q], 0.f);
            }
        }
        #pragma unroll
        for (int q = 0; q < 4; ++q) {
            const int e = 4 * g + q;
            const int m = (e & 7) << 3;
            W[1024 + e*64 + (( 0 + r) ^ m)] = (_Float16)s0[q];
            W[1024 + e*64 + ((16 + r) ^ m)] = (_Float16)s1[q];
            W[1024 + e*64 + ((32 + r) ^ m)] = (_Float16)s2[q];
            W[1024 + e*64 + ((48 + r) ^ m)] = (_Float16)s3[q];
        }
    }

    // ================= C: pn = sn @ pnW2 + 16*pnb2 -> PN ======================
    {
        h8v a0 = *(const h8v*)&W[r*64 + (( 0 + 8*g) ^ sw8)];
        h8v a1 = *(const h8v*)&W[r*64 + ((32 + 8*g) ^ sw8)];
        h8v b0 = FB[256 + 0*64 + l];
        h8v b1 = FB[256 + 1*64 + l];
        const float bb = 16.f * pnb2[r];
        f4v c = {bb, bb, bb, bb};
        prio1();
        f4v d = MFMA(a1, b1, MFMA(a0, b0, c));
        prio0();
        #pragma unroll
        for (int q = 0; q < 4; ++q) {
            const int row = 4 * g + q;
            W[2048 + row*32 + (r ^ ((row&3)<<3))] = (_Float16)d[q];
        }
    }
    // ================= D1: t = relu(pn @ rnW1 + rnb1) -> POOL =================
    {
        h8v a = *(const h8v*)&W[2048 + r*32 + ((8*g) ^ sw4)];
        #pragma unroll
        for (int nt = 0; nt < 4; ++nt) {
            h8v b = FB[384 + nt*64 + l];
            const float bb = rnb1[16*nt + r];
            f4v c = {bb, bb, bb, bb};
            prio1();
            f4v d = MFMA(a, b, c);
            prio0();
            #pragma unroll
            for (int q = 0; q < 4; ++q) {
                const int row = 4 * g + q;
                W[row*64 + ((16*nt + r) ^ ((row&7)<<3))] = (_Float16)fmaxf(d[q], 0.f);
            }
        }
    }
    // ================= D2: rn = t @ rnW2 + rnb2 -> HB cols 0..7 ===============
    {
        h8v a0 = *(const h8v*)&W[r*64 + (( 0 + 8*g) ^ sw8)];
        h8v a1 = *(const h8v*)&W[r*64 + ((32 + 8*g) ^ sw8)];
        h8v b0 = FB[640 + 0*64 + l];
        h8v b1 = FB[640 + 1*64 + l];
        const float bb = (r < 8) ? rnb2[r & 7] : 0.f;
        f4v c = {bb, bb, bb, bb};
        prio1();
        f4v d = MFMA(a1, b1, MFMA(a0, b0, c));
        prio0();
        if (r < 8) {
            #pragma unroll
            for (int q = 0; q < 4; ++q) {
                const int row = 4 * g + q;
                W[2560 + row*32 + (r ^ ((row&3)<<3))] = (_Float16)d[q];
            }
        }
    }
    // ================= C': po = so @ poW2 + 32*pob2 -> PN =====================
    {
        h8v a0 = *(const h8v*)&W[1024 + r*64 + (( 0 + 8*g) ^ sw8)];
        h8v a1 = *(const h8v*)&W[1024 + r*64 + ((32 + 8*g) ^ sw8)];
        h8v b0 = FB[1024 + 0*64 + l];
        h8v b1 = FB[1024 + 1*64 + l];
        const float bb = 32.f * pob2[r];
        f4v c = {bb, bb, bb, bb};
        prio1();
        f4v d = MFMA(a1, b1, MFMA(a0, b0, c));
        prio0();
        #pragma unroll
        for (int q = 0; q < 4; ++q) {
            const int row = 4 * g + q;
            W[2048 + row*32 + (r ^ ((row&3)<<3))] = (_Float16)d[q];
        }
    }
    // ================= D1': t2 = relu(po @ roW1 + rob1) -> POOL ===============
    {
        h8v a = *(const h8v*)&W[2048 + r*32 + ((8*g) ^ sw4)];
        #pragma unroll
        for (int nt = 0; nt < 4; ++nt) {
            h8v b = FB[1152 + nt*64 + l];
            const float bb = rob1[16*nt + r];
            f4v c = {bb, bb, bb, bb};
            prio1();
            f4v d = MFMA(a, b, c);
            prio0();
            #pragma unroll
            for (int q = 0; q < 4; ++q) {
                const int row = 4 * g + q;
                W[row*64 + ((16*nt + r) ^ ((row&7)<<3))] = (_Float16)fmaxf(d[q], 0.f);
            }
        }
    }
    // ================= D2': ro = t2 @ roW2 + rob2 -> HB cols 8..15 ============
    {
        h8v a0 = *(const h8v*)&W[r*64 + (( 0 + 8*g) ^ sw8)];
        h8v a1 = *(const h8v*)&W[r*64 + ((32 + 8*g) ^ sw8)];
        h8v b0 = FB[1408 + 0*64 + l];
        h8v b1 = FB[1408 + 1*64 + l];
        const float bb = (r < 8) ? rob2[r & 7] : 0.f;
        f4v c = {bb, bb, bb, bb};
        prio1();
        f4v d = MFMA(a1, b1, MFMA(a0, b0, c));
        prio0();
        if (r < 8) {
            #pragma unroll
            for (int q = 0; q < 4; ++q) {
                const int row = 4 * g + q;
                W[2560 + row*32 + ((8 + r) ^ ((row&3)<<3))] = (_Float16)d[q];
            }
        }
    }
    // ================= goal cols 16,17 into HB (from XS) ======================
    if (g == 0) {
        const h2 gv = u2h(XS[rowb + 64]);
        W[2560 + r*32 + (16 ^ sw4)] = gv[0];
        W[2560 + r*32 + (17 ^ sw4)] = gv[1];
    }
    // ================= F: ha = relu(h @ psW1 + psb1) -> TBUF ==================
    {
        h8v a = *(const h8v*)&W[2560 + r*32 + ((8*g) ^ sw4)];
        #pragma unroll
        for (int nt = 0; nt < 4; ++nt) {
            h8v b = FB[1536 + nt*64 + l];
            const float bb = psb1[16*nt + r];
            f4v c = {bb, bb, bb, bb};
            prio1();
            f4v d = MFMA(a, b, c);
            prio0();
            #pragma unroll
            for (int q = 0; q < 4; ++q) {
                const int row = 4 * g + q;
                W[1024 + row*64 + ((16*nt + r) ^ ((row&7)<<3))] = (_Float16)fmaxf(d[q], 0.f);
            }
        }
    }
    // ================= G1: t2 = relu(ha @ psW2 + psb2) -> POOL ================
    {
        h8v a0 = *(const h8v*)&W[1024 + r*64 + (( 0 + 8*g) ^ sw8)];
        h8v a1 = *(const h8v*)&W[1024 + r*64 + ((32 + 8*g) ^ sw8)];
        #pragma unroll
        for (int nt = 0; nt < 4; ++nt) {
            h8v b0 = FB[1792 + (0*4 + nt)*64 + l];
            h8v b1 = FB[1792 + (1*4 + nt)*64 + l];
            const float bb = psb2[16*nt + r];
            f4v c = {bb, bb, bb, bb};
            prio1();
            f4v d = MFMA(a1, b1, MFMA(a0, b0, c));
            prio0();
            #pragma unroll
            for (int q = 0; q < 4; ++q) {
                const int row = 4 * g + q;
                W[row*64 + ((16*nt + r) ^ ((row&7)<<3))] = (_Float16)fmaxf(d[q], 0.f);
            }
        }
    }
    // ================= G2 + finale ============================================
    f4v dOut;
    {
        h8v a0 = *(const h8v*)&W[r*64 + (( 0 + 8*g) ^ sw8)];
        h8v a1 = *(const h8v*)&W[r*64 + ((32 + 8*g) ^ sw8)];
        h8v b0 = FB[2304 + 0*64 + l];
        h8v b1 = FB[2304 + 1*64 + l];
        const float bb = (r < 2) ? psb3[r & 1] : 0.f;
        f4v c = {bb, bb, bb, bb};
        prio1();
        dOut = MFMA(a1, b1, MFMA(a0, b0, c));
        prio0();
    }
    if (r < 2) {
        #pragma unroll
        for (int q = 0; q < 4; ++q) {
            const int e = 4 * g + q;
            const float o = dOut[q];
            const float bar = barf[e*2 + r];
            const float nz = noise[2 * (size_t)(eb + e) + r];
            const float av = tanhf(2.f * tanhf(o) + bar + nz);
            out[2 * (size_t)(eb + e) + r] = 2.f * av;
        }
    }
}

extern "C" void kernel_launch(void* const* d_in, const int* in_sizes, int n_in,
                              void* d_out, int out_size, void* d_ws, size_t ws_size,
                              hipStream_t stream) {
    const float* x    = (const float*)d_in[0];
    const float* nz   = (const float*)d_in[1];
    const float* pnW1 = (const float*)d_in[2];
    const float* pnb1 = (const float*)d_in[3];
    const float* pnW2 = (const float*)d_in[4];
    const float* pnb2 = (const float*)d_in[5];
    const float* rnW1 = (const float*)d_in[6];
    const float* rnb1 = (const float*)d_in[7];
    const float* rnW2 = (const float*)d_in[8];
    const float* rnb2 = (const float*)d_in[9];
    const float* poW1 = (const float*)d_in[10];
    const float* pob1 = (const float*)d_in[11];
    const float* poW2 = (const float*)d_in[12];
    const float* pob2 = (const float*)d_in[13];
    const float* roW1 = (const float*)d_in[14];
    const float* rob1 = (const float*)d_in[15];
    const float* roW2 = (const float*)d_in[16];
    const float* rob2 = (const float*)d_in[17];
    const float* psW1 = (const float*)d_in[18];
    const float* psb1 = (const float*)d_in[19];
    const float* psW2 = (const float*)d_in[20];
    const float* psb2 = (const float*)d_in[21];
    const float* psW3 = (const float*)d_in[22];
    const float* psb3 = (const float*)d_in[23];

    unsigned* ws = (unsigned*)d_ws;
    hipLaunchKernelGGL(prep_frags, dim3(38), dim3(256), 0, stream,
        pnW1, pnW2, rnW1, rnW2, poW1, poW2, roW1, roW2, psW1, psW2, psW3, ws);

    const int b = in_sizes[0] / XCOLS;
    hipLaunchKernelGGL(barrier_net_kernel, dim3(b / 16), dim3(64), 0, stream,
        x, nz, pnb1, pnb2, rnb1, rnb2, pob1, pob2, rob1, rob2,
        psb1, psb2, psb3, ws, (float*)d_out);
}

// Round 16
// 44.613 us; speedup vs baseline: 1.3209x; 1.0304x over previous
//
#include <hip/hip_runtime.h>

#define NN 16
#define NO 32
#define XCOLS 133

typedef _Float16 h8v __attribute__((ext_vector_type(8)));
typedef _Float16 h2 __attribute__((ext_vector_type(2)));
typedef float f4v __attribute__((ext_vector_type(4)));
typedef unsigned ui4 __attribute__((ext_vector_type(4)));
typedef float f2u __attribute__((ext_vector_type(2), aligned(4)));

static __device__ __forceinline__ f4v MFMA(h8v a, h8v b, f4v c) {
    return __builtin_amdgcn_mfma_f32_16x16x32_f16(a, b, c, 0, 0, 0);
}
static __device__ __forceinline__ unsigned pkbits(float a, float b) {
    return __builtin_bit_cast(unsigned, __builtin_amdgcn_cvt_pkrtz(a, b));
}
static __device__ __forceinline__ h2 u2h(unsigned v) { return __builtin_bit_cast(h2, v); }

// ---------------------------------------------------------------------------
// prep (parallel, verified): pack weights into MFMA B-fragment arrays.
// B[k][col]: col = 16*nt + (lane&15), k = 32*kc + 8*(lane>>4) + j; zero-padded.
// ---------------------------------------------------------------------------
__global__ void prep_frags(
    const float* __restrict__ pnW1, const float* __restrict__ pnW2,
    const float* __restrict__ rnW1, const float* __restrict__ rnW2,
    const float* __restrict__ poW1, const float* __restrict__ poW2,
    const float* __restrict__ roW1, const float* __restrict__ roW2,
    const float* __restrict__ psW1, const float* __restrict__ psW2,
    const float* __restrict__ psW3, unsigned* __restrict__ ws)
{
    const float* Ws[11] = {pnW1,pnW2,rnW1,rnW2,poW1,poW2,roW1,roW2,psW1,psW2,psW3};
    const int Kr[11]   = {4,64,16,64,2,64,16,64,18,64,64};
    const int Nr[11]   = {64,16,64,8,64,16,64,8,64,64,2};
    const int nkc[11]  = {1,2,1,2,1,2,1,2,1,2,2};
    const int nnt[11]  = {4,1,4,1,4,1,4,1,4,4,1};
    const int base[11] = {0,1024,1536,2560,3072,4096,4608,5632,6144,7168,9216};

    const int gid = blockIdx.x * 256 + threadIdx.x;   // 0..9727
    int start = 0;
    #pragma unroll
    for (int a2 = 0; a2 < 11; ++a2) {
        const int n = nkc[a2] * nnt[a2] * 256;
        if (gid >= start && gid < start + n) {
            const int i = gid - start;
            const float* Wm = Ws[a2];
            const int K = Kr[a2], N = Nr[a2], nt_n = nnt[a2];
            const int d = i & 3, lane = (i >> 2) & 63, t = i >> 8;
            const int nt = t % nt_n, kc = t / nt_n;
            const int k = kc * 32 + 8 * (lane >> 4) + 2 * d;
            const int col = nt * 16 + (lane & 15);
            const float v0 = (k     < K && col < N) ? Wm[(k    ) * N + col] : 0.f;
            const float v1 = (k + 1 < K && col < N) ? Wm[(k + 1) * N + col] : 0.f;
            ws[base[a2] + i] = pkbits(v0, v1);
        }
        start += n;
    }
}

// ---------------------------------------------------------------------------
// main (measured best, R11): 64-thread (1-wave) blocks, 16 elements each.
// x burst-staged into XS[16][66] via 16 coalesced 512B row-loads (statically
// indexed regs, no scratch); L1 point-loops (elements-as-rows, in-register
// relu+pool); dense chain via per-wave LDS with XOR-swizzled fragment layout.
// LDS: XS 4224B + W 6272B = 10496B.
// ---------------------------------------------------------------------------
__global__ __launch_bounds__(64, 4) void barrier_net_kernel(
    const float* __restrict__ x, const float* __restrict__ noise,
    const float* __restrict__ pnb1, const float* __restrict__ pnb2,
    const float* __restrict__ rnb1, const float* __restrict__ rnb2,
    const float* __restrict__ pob1, const float* __restrict__ pob2,
    const float* __restrict__ rob1, const float* __restrict__ rob2,
    const float* __restrict__ psb1, const float* __restrict__ psb2,
    const float* __restrict__ psb3,
    const unsigned* __restrict__ wsu, float* __restrict__ out)
{
    __shared__ unsigned XS[16 * 66];   // staged f16 pairs: row rr, pair p at XS[rr*66+p]
    __shared__ _Float16 W[3136];       // POOL@0, TBUF@1024, PN@2048, HB@2560, barf@3072

    const int l = threadIdx.x;
    const int r = l & 15;
    const int g = l >> 4;
    const int eb = blockIdx.x * 16;

    float* barf = (float*)(W + 3072);
    const h8v* FB = (const h8v*)wsu;

    // ---- burst-stage x: 16 rows x 128 floats (cols 5..132) + goal (cols 1,2)
    {
        const float* base = x + (size_t)eb * XCOLS;
        f2u raw[16];
        #pragma unroll
        for (int it = 0; it < 16; ++it)
            raw[it] = *(const f2u*)(base + (size_t)it * XCOLS + 5 + 2 * l);
        f2u graw = {0.f, 0.f};
        if (l < 16) graw = *(const f2u*)(base + (size_t)l * XCOLS + 1);
        #pragma unroll
        for (int it = 0; it < 16; ++it)
            XS[it * 66 + l] = pkbits(raw[it][0], raw[it][1]);
        if (l < 16) XS[l * 66 + 64] = pkbits(graw[0], graw[1]);
    }

    {   // zero PN+HB (2048..3072 f16 = 512 dwords, 8/lane)
        unsigned* z = (unsigned*)(W + 2048);
        #pragma unroll
        for (int i = 0; i < 8; ++i) z[l + 64 * i] = 0u;
    }

    const int rowb = r * 66;
    const int sw8 = (r & 7) << 3;
    const int sw4 = (r & 3) << 3;

    // ================= barrier pass (dedup'd across g, from XS) ===============
    {
        float bq0 = 0.f, bq1 = 0.f;
        #pragma unroll
        for (int jj = 0; jj < 4; ++jj) {
            const h2 v = u2h(XS[rowb + 2 * (4 * g + jj)]);     // neighbor j pos
            const float v0 = (float)v[0], v1 = (float)v[1];
            const float nrm = sqrtf(v0*v0 + v1*v1);
            const float cc = 0.01f * __builtin_amdgcn_rcpf(nrm * (nrm - 0.3f));
            bq0 -= cc * v0; bq1 -= cc * v1;
        }
        #pragma unroll
        for (int jj = 0; jj < 8; ++jj) {
            const h2 v = u2h(XS[rowb + 32 + 8 * g + jj]);      // obstacle j pos
            const float v0 = (float)v[0], v1 = (float)v[1];
            const float nrm = sqrtf(v0*v0 + v1*v1);
            const float cc = 0.01f * __builtin_amdgcn_rcpf(nrm * (nrm - 0.5f));
            bq0 -= cc * v0; bq1 -= cc * v1;
        }
        bq0 += __shfl_xor(bq0, 16); bq0 += __shfl_xor(bq0, 32);
        bq1 += __shfl_xor(bq1, 16); bq1 += __shfl_xor(bq1, 32);
        if (g == 0) { barf[2*r] = bq0; barf[2*r + 1] = bq1; }
    }

    // ================= L1 neighbor: point-loop from XS ========================
    {
        const h8v B0 = FB[0*64 + l], B1 = FB[1*64 + l];
        const h8v B2 = FB[2*64 + l], B3 = FB[3*64 + l];
        const f4v c0 = {pnb1[r], pnb1[r], pnb1[r], pnb1[r]};
        const f4v c1 = {pnb1[16+r], pnb1[16+r], pnb1[16+r], pnb1[16+r]};
        const f4v c2 = {pnb1[32+r], pnb1[32+r], pnb1[32+r], pnb1[32+r]};
        const f4v c3 = {pnb1[48+r], pnb1[48+r], pnb1[48+r], pnb1[48+r]};
        f4v s0 = {0,0,0,0}, s1 = {0,0,0,0}, s2 = {0,0,0,0}, s3 = {0,0,0,0};
        #pragma unroll 4
        for (int j = 0; j < NN; ++j) {
            const uint2 np = *(const uint2*)&XS[rowb + 2 * j];  // 4 feats (8B-aligned)
            ui4 au = {np.x, np.y, 0u, 0u};
            const h8v a = __builtin_bit_cast(h8v, au);
            const f4v d0 = MFMA(a, B0, c0);
            const f4v d1 = MFMA(a, B1, c1);
            const f4v d2 = MFMA(a, B2, c2);
            const f4v d3 = MFMA(a, B3, c3);
            #pragma unroll
            for (int q = 0; q < 4; ++q) {
                s0[q] += fmaxf(d0[q], 0.f); s1[q] += fmaxf(d1[q], 0.f);
                s2[q] += fmaxf(d2[q], 0.f); s3[q] += fmaxf(d3[q], 0.f);
            }
        }
        #pragma unroll
        for (int q = 0; q < 4; ++q) {
            const int e = 4 * g + q;
            const int m = (e & 7) << 3;
            W[e*64 + (( 0 + r) ^ m)] = (_Float16)s0[q];
            W[e*64 + ((16 + r) ^ m)] = (_Float16)s1[q];
            W[e*64 + ((32 + r) ^ m)] = (_Float16)s2[q];
            W[e*64 + ((48 + r) ^ m)] = (_Float16)s3[q];
        }
    }

    // ================= L1 obstacle: point-loop from XS, 2 pts/iter ============
    {
        const h8v B0 = FB[768 + 0*64 + l], B1 = FB[768 + 1*64 + l];
        const h8v B2 = FB[768 + 2*64 + l], B3 = FB[768 + 3*64 + l];
        const f4v c0 = {pob1[r], pob1[r], pob1[r], pob1[r]};
        const f4v c1 = {pob1[16+r], pob1[16+r], pob1[16+r], pob1[16+r]};
        const f4v c2 = {pob1[32+r], pob1[32+r], pob1[32+r], pob1[32+r]};
        const f4v c3 = {pob1[48+r], pob1[48+r], pob1[48+r], pob1[48+r]};
        f4v s0 = {0,0,0,0}, s1 = {0,0,0,0}, s2 = {0,0,0,0}, s3 = {0,0,0,0};
        #pragma unroll 2
        for (int t = 0; t < 16; ++t) {
            const uint2 op = *(const uint2*)&XS[rowb + 32 + 2 * t];  // 2 points
            ui4 au0 = {op.x, 0u, 0u, 0u};
            ui4 au1 = {op.y, 0u, 0u, 0u};
            const h8v a0 = __builtin_bit_cast(h8v, au0);
            const h8v a1 = __builtin_bit_cast(h8v, au1);
            const f4v d0 = MFMA(a0, B0, c0); const f4v e0 = MFMA(a1, B0, c0);
            const f4v d1 = MFMA(a0, B1, c1); const f4v e1 = MFMA(a1, B1, c1);
            const f4v d2 = MFMA(a0, B2, c2); const f4v e2 = MFMA(a1, B2, c2);
            const f4v d3 = MFMA(a0, B3, c3); const f4v e3 = MFMA(a1, B3, c3);
            #pragma unroll
            for (int q = 0; q < 4; ++q) {
                s0[q] += fmaxf(d0[q], 0.f) + fmaxf(e0[q], 0.f);
                s1[q] += fmaxf(d1[q], 0.f) + fmaxf(e1[q], 0.f);
                s2[q] += fmaxf(d2[q], 0.f) + fmaxf(e2[q], 0.f);
                s3[q] += fmaxf(d3[q], 0.f) + fmaxf(e3[q], 0.f);
            }
        }
        #pragma unroll
        for (int q = 0; q < 4; ++q) {
            const int e = 4 * g + q;
            const int m = (e & 7) << 3;
            W[1024 + e*64 + (( 0 + r) ^ m)] = (_Float16)s0[q];
            W[1024 + e*64 + ((16 + r) ^ m)] = (_Float16)s1[q];
            W[1024 + e*64 + ((32 + r) ^ m)] = (_Float16)s2[q];
            W[1024 + e*64 + ((48 + r) ^ m)] = (_Float16)s3[q];
        }
    }

    // ================= C: pn = sn @ pnW2 + 16*pnb2 -> PN ======================
    {
        h8v a0 = *(const h8v*)&W[r*64 + (( 0 + 8*g) ^ sw8)];
        h8v a1 = *(const h8v*)&W[r*64 + ((32 + 8*g) ^ sw8)];
        h8v b0 = FB[256 + 0*64 + l];
        h8v b1 = FB[256 + 1*64 + l];
        const float bb = 16.f * pnb2[r];
        f4v c = {bb, bb, bb, bb};
        f4v d = MFMA(a1, b1, MFMA(a0, b0, c));
        #pragma unroll
        for (int q = 0; q < 4; ++q) {
            const int row = 4 * g + q;
            W[2048 + row*32 + (r ^ ((row&3)<<3))] = (_Float16)d[q];
        }
    }
    // ================= D1: t = relu(pn @ rnW1 + rnb1) -> POOL =================
    {
        h8v a = *(const h8v*)&W[2048 + r*32 + ((8*g) ^ sw4)];
        #pragma unroll
        for (int nt = 0; nt < 4; ++nt) {
            h8v b = FB[384 + nt*64 + l];
            const float bb = rnb1[16*nt + r];
            f4v c = {bb, bb, bb, bb};
            f4v d = MFMA(a, b, c);
            #pragma unroll
            for (int q = 0; q < 4; ++q) {
                const int row = 4 * g + q;
                W[row*64 + ((16*nt + r) ^ ((row&7)<<3))] = (_Float16)fmaxf(d[q], 0.f);
            }
        }
    }
    // ================= D2: rn = t @ rnW2 + rnb2 -> HB cols 0..7 ===============
    {
        h8v a0 = *(const h8v*)&W[r*64 + (( 0 + 8*g) ^ sw8)];
        h8v a1 = *(const h8v*)&W[r*64 + ((32 + 8*g) ^ sw8)];
        h8v b0 = FB[640 + 0*64 + l];
        h8v b1 = FB[640 + 1*64 + l];
        const float bb = (r < 8) ? rnb2[r & 7] : 0.f;
        f4v c = {bb, bb, bb, bb};
        f4v d = MFMA(a1, b1, MFMA(a0, b0, c));
        if (r < 8) {
            #pragma unroll
            for (int q = 0; q < 4; ++q) {
                const int row = 4 * g + q;
                W[2560 + row*32 + (r ^ ((row&3)<<3))] = (_Float16)d[q];
            }
        }
    }
    // ================= C': po = so @ poW2 + 32*pob2 -> PN =====================
    {
        h8v a0 = *(const h8v*)&W[1024 + r*64 + (( 0 + 8*g) ^ sw8)];
        h8v a1 = *(const h8v*)&W[1024 + r*64 + ((32 + 8*g) ^ sw8)];
        h8v b0 = FB[1024 + 0*64 + l];
        h8v b1 = FB[1024 + 1*64 + l];
        const float bb = 32.f * pob2[r];
        f4v c = {bb, bb, bb, bb};
        f4v d = MFMA(a1, b1, MFMA(a0, b0, c));
        #pragma unroll
        for (int q = 0; q < 4; ++q) {
            const int row = 4 * g + q;
            W[2048 + row*32 + (r ^ ((row&3)<<3))] = (_Float16)d[q];
        }
    }
    // ================= D1': t2 = relu(po @ roW1 + rob1) -> POOL ===============
    {
        h8v a = *(const h8v*)&W[2048 + r*32 + ((8*g) ^ sw4)];
        #pragma unroll
        for (int nt = 0; nt < 4; ++nt) {
            h8v b = FB[1152 + nt*64 + l];
            const float bb = rob1[16*nt + r];
            f4v c = {bb, bb, bb, bb};
            f4v d = MFMA(a, b, c);
            #pragma unroll
            for (int q = 0; q < 4; ++q) {
                const int row = 4 * g + q;
                W[row*64 + ((16*nt + r) ^ ((row&7)<<3))] = (_Float16)fmaxf(d[q], 0.f);
            }
        }
    }
    // ================= D2': ro = t2 @ roW2 + rob2 -> HB cols 8..15 ============
    {
        h8v a0 = *(const h8v*)&W[r*64 + (( 0 + 8*g) ^ sw8)];
        h8v a1 = *(const h8v*)&W[r*64 + ((32 + 8*g) ^ sw8)];
        h8v b0 = FB[1408 + 0*64 + l];
        h8v b1 = FB[1408 + 1*64 + l];
        const float bb = (r < 8) ? rob2[r & 7] : 0.f;
        f4v c = {bb, bb, bb, bb};
        f4v d = MFMA(a1, b1, MFMA(a0, b0, c));
        if (r < 8) {
            #pragma unroll
            for (int q = 0; q < 4; ++q) {
                const int row = 4 * g + q;
                W[2560 + row*32 + ((8 + r) ^ ((row&3)<<3))] = (_Float16)d[q];
            }
        }
    }
    // ================= goal cols 16,17 into HB (from XS) ======================
    if (g == 0) {
        const h2 gv = u2h(XS[rowb + 64]);
        W[2560 + r*32 + (16 ^ sw4)] = gv[0];
        W[2560 + r*32 + (17 ^ sw4)] = gv[1];
    }
    // ================= F: ha = relu(h @ psW1 + psb1) -> TBUF ==================
    {
        h8v a = *(const h8v*)&W[2560 + r*32 + ((8*g) ^ sw4)];
        #pragma unroll
        for (int nt = 0; nt < 4; ++nt) {
            h8v b = FB[1536 + nt*64 + l];
            const float bb = psb1[16*nt + r];
            f4v c = {bb, bb, bb, bb};
            f4v d = MFMA(a, b, c);
            #pragma unroll
            for (int q = 0; q < 4; ++q) {
                const int row = 4 * g + q;
                W[1024 + row*64 + ((16*nt + r) ^ ((row&7)<<3))] = (_Float16)fmaxf(d[q], 0.f);
            }
        }
    }
    // ================= G1: t2 = relu(ha @ psW2 + psb2) -> POOL ================
    {
        h8v a0 = *(const h8v*)&W[1024 + r*64 + (( 0 + 8*g) ^ sw8)];
        h8v a1 = *(const h8v*)&W[1024 + r*64 + ((32 + 8*g) ^ sw8)];
        #pragma unroll
        for (int nt = 0; nt < 4; ++nt) {
            h8v b0 = FB[1792 + (0*4 + nt)*64 + l];
            h8v b1 = FB[1792 + (1*4 + nt)*64 + l];
            const float bb = psb2[16*nt + r];
            f4v c = {bb, bb, bb, bb};
            f4v d = MFMA(a1, b1, MFMA(a0, b0, c));
            #pragma unroll
            for (int q = 0; q < 4; ++q) {
                const int row = 4 * g + q;
                W[row*64 + ((16*nt + r) ^ ((row&7)<<3))] = (_Float16)fmaxf(d[q], 0.f);
            }
        }
    }
    // ================= G2 + finale ============================================
    f4v dOut;
    {
        h8v a0 = *(const h8v*)&W[r*64 + (( 0 + 8*g) ^ sw8)];
        h8v a1 = *(const h8v*)&W[r*64 + ((32 + 8*g) ^ sw8)];
        h8v b0 = FB[2304 + 0*64 + l];
        h8v b1 = FB[2304 + 1*64 + l];
        const float bb = (r < 2) ? psb3[r & 1] : 0.f;
        f4v c = {bb, bb, bb, bb};
        dOut = MFMA(a1, b1, MFMA(a0, b0, c));
    }
    if (r < 2) {
        #pragma unroll
        for (int q = 0; q < 4; ++q) {
            const int e = 4 * g + q;
            const float o = dOut[q];
            const float bar = barf[e*2 + r];
            const float nz = noise[2 * (size_t)(eb + e) + r];
            const float av = tanhf(2.f * tanhf(o) + bar + nz);
            out[2 * (size_t)(eb + e) + r] = 2.f * av;
        }
    }
}

extern "C" void kernel_launch(void* const* d_in, const int* in_sizes, int n_in,
                              void* d_out, int out_size, void* d_ws, size_t ws_size,
                              hipStream_t stream) {
    const float* x    = (const float*)d_in[0];
    const float* nz   = (const float*)d_in[1];
    const float* pnW1 = (const float*)d_in[2];
    const float* pnb1 = (const float*)d_in[3];
    const float* pnW2 = (const float*)d_in[4];
    const float* pnb2 = (const float*)d_in[5];
    const float* rnW1 = (const float*)d_in[6];
    const float* rnb1 = (const float*)d_in[7];
    const float* rnW2 = (const float*)d_in[8];
    const float* rnb2 = (const float*)d_in[9];
    const float* poW1 = (const float*)d_in[10];
    const float* pob1 = (const float*)d_in[11];
    const float* poW2 = (const float*)d_in[12];
    const float* pob2 = (const float*)d_in[13];
    const float* roW1 = (const float*)d_in[14];
    const float* rob1 = (const float*)d_in[15];
    const float* roW2 = (const float*)d_in[16];
    const float* rob2 = (const float*)d_in[17];
    const float* psW1 = (const float*)d_in[18];
    const float* psb1 = (const float*)d_in[19];
    const float* psW2 = (const float*)d_in[20];
    const float* psb2 = (const float*)d_in[21];
    const float* psW3 = (const float*)d_in[22];
    const float* psb3 = (const float*)d_in[23];

    unsigned* ws = (unsigned*)d_ws;
    hipLaunchKernelGGL(prep_frags, dim3(38), dim3(256), 0, stream,
        pnW1, pnW2, rnW1, rnW2, poW1, poW2, roW1, roW2, psW1, psW2, psW3, ws);

    const int b = in_sizes[0] / XCOLS;
    hipLaunchKernelGGL(barrier_net_kernel, dim3(b / 16), dim3(64), 0, stream,
        x, nz, pnb1, pnb2, rnb1, rnb2, pob1, pob2, rob1, rob2,
        psb1, psb2, psb3, ws, (float*)d_out);
}